// Round 1
// 1695.387 us; speedup vs baseline: 2.1478x; 2.1478x over previous
//
#include <hip/hip_runtime.h>
#include <hip/hip_bf16.h>

#define N_NODES 20000
#define R_REL   48
#define NBASES  12
#define E_EDGES 640000
#define EPB     16
#define SC_CHUNK 2048

// ---------- dual-dtype scalar access (flag: 1 = fp32, 0 = bf16) -------------
__device__ inline float loadF(const void* p, long long idx, int isf32) {
    if (isf32 != 0) return ((const float*)p)[idx];
    return __bfloat162float(((const __hip_bfloat16*)p)[idx]);
}

__device__ inline void storeF(void* p, long long idx, int isf32, float v) {
    if (isf32 != 0) ((float*)p)[idx] = v;
    else ((__hip_bfloat16*)p)[idx] = __float2bfloat16(v);
}

// ---------- dtype probe ------------------------------------------------------
__global__ void detect_dtype(const void* emb, int* flag) {
    if (threadIdx.x == 0 && blockIdx.x == 0) {
        const unsigned short* h = (const unsigned short*)emb;
        int f32 = 0;
        for (int k = 0; k < 256; k++) {
            unsigned int bits = ((unsigned int)h[k]) << 16;
            float v = __uint_as_float(bits);
            if (!(fabsf(v) < 1000.0f)) f32 = 1;   // huge/NaN -> fp32 data
        }
        *flag = f32;
    }
}

// ---------- zero helpers -----------------------------------------------------
__global__ void zero_f32(float* p, int n) {
    int i = blockIdx.x * 256 + threadIdx.x;
    if (i < n) p[i] = 0.0f;
}

__global__ void zero_i32(int* p, int n) {
    int i = blockIdx.x * 256 + threadIdx.x;
    if (i < n) p[i] = 0;
}

// ---------- edge prep --------------------------------------------------------
// cnt only: scattered atomics over R*N floats (L2-resident, low contention).
// The per-relation histogram is derived afterwards by hist_reduce -- the
// previous version's atomicAdd(&hist[t],1) serialized 640K atomics on ~3
// cache lines (932 us measured).
__global__ void count_kernel(const int* dst, const int* typ, float* cnt) {
    int e = blockIdx.x * 256 + threadIdx.x;
    if (e < E_EDGES) {
        int t = typ[e];
        atomicAdd(&cnt[(long long)t * N_NODES + dst[e]], 1.0f);
    }
}

// hist[r] = sum over d of cnt[r*N+d]  (counts are exact small integers)
__global__ void hist_reduce(const float* cnt, int* hist) {
    __shared__ float sh[256];
    int r = blockIdx.x;
    float acc = 0.0f;
    for (int i = threadIdx.x; i < N_NODES; i += 256)
        acc += cnt[(long long)r * N_NODES + i];
    sh[threadIdx.x] = acc;
    __syncthreads();
    for (int s = 128; s > 0; s >>= 1) {
        if (threadIdx.x < s) sh[threadIdx.x] += sh[threadIdx.x + s];
        __syncthreads();
    }
    if (threadIdx.x == 0) hist[r] = (int)(sh[0] + 0.5f);
}

__global__ void inv_kernel(float* p) {
    int i = blockIdx.x * 256 + threadIdx.x;   // < R*N exactly
    float c = p[i];
    p[i] = (c > 0.0f) ? (1.0f / c) : 0.0f;
}

// cursorP is line-padded: one counter per 32 ints (128 B) to avoid
// same-line serialization on the chunk reservations.
__global__ void prefix_kernel(const int* hist, int* bins, int* cursorP) {
    if (threadIdx.x == 0 && blockIdx.x == 0) {
        int acc = 0;
        for (int r = 0; r < R_REL; r++) {
            bins[r] = acc;
            cursorP[r * 32] = acc;
            acc += hist[r];
        }
        bins[R_REL] = acc;
    }
}

// Block-chunk reservation scatter: LDS histogram of a 2048-edge chunk,
// ONE global atomic per (block, relation) to reserve the output range,
// then conflict-free writes. 313*48 = 15K global atomics vs 640K before.
__global__ __launch_bounds__(256) void scatter_chunk(
        const int* src, const int* dst, const int* typ,
        int* cursorP, int* s_src, int* s_dst) {
    __shared__ int sh_cnt[R_REL];
    __shared__ int sh_base[R_REL];
    int b0 = blockIdx.x * SC_CHUNK;
    int tid = threadIdx.x;
    for (int t = tid; t < R_REL; t += 256) sh_cnt[t] = 0;
    __syncthreads();

    int myt[8];
    int myloc[8];
#pragma unroll 8
    for (int k = 0; k < 8; k++) {
        int e = b0 + k * 256 + tid;
        if (e < E_EDGES) {
            int t = typ[e];
            myt[k] = t;
            myloc[k] = atomicAdd(&sh_cnt[t], 1);
        } else {
            myt[k] = -1;
            myloc[k] = 0;
        }
    }
    __syncthreads();
    for (int t = tid; t < R_REL; t += 256)
        sh_base[t] = atomicAdd(&cursorP[t * 32], sh_cnt[t]);
    __syncthreads();
#pragma unroll 8
    for (int k = 0; k < 8; k++) {
        if (myt[k] >= 0) {
            int e = b0 + k * 256 + tid;
            int p = sh_base[myt[k]] + myloc[k];
            s_src[p] = src[e];
            s_dst[p] = dst[e];
        }
    }
}

// ---------- W build: W[r][i][o] = sum_b comp[r][b]*basis[b][i][o] -----------
__global__ void build_w(const void* comp, const void* basis,
                        __hip_bfloat16* W, const int* flagp) {
    int r = blockIdx.x;
    int idx = blockIdx.y * 256 + threadIdx.x;   // 0..16383 = i*128+o
    int isf32 = *flagp;
    float acc = 0.0f;
    for (int b = 0; b < NBASES; b++) {
        acc += loadF(comp, r * NBASES + b, isf32) *
               loadF(basis, b * 16384 + idx, isf32);
    }
    W[((long long)r << 14) + idx] = __float2bfloat16(acc);
}

// ---------- root: outf[n][o] = bias[o] + sum_i x[n][i]*root[i][o] -----------
__global__ __launch_bounds__(128) void root_valu(
        const void* x, int xbase, int xld,
        const void* root, const void* bias,
        float* outf, const int* flagp) {
    __shared__ float xs[128];
    int n = blockIdx.x;
    int o = threadIdx.x;
    int isf32 = *flagp;
    xs[o] = loadF(x, (long long)xbase + (long long)n * xld + o, isf32);
    __syncthreads();
    float acc = loadF(bias, o, isf32);
    for (int i = 0; i < 128; i++)
        acc += xs[i] * loadF(root, i * 128 + o, isf32);
    outf[(long long)n * 128 + o] = acc;
}

// ---------- edge: outf[dst] += inv * (x[src] @ W_r) -------------------------
__global__ __launch_bounds__(256) void edge_valu(
        const int* s_src, const int* s_dst, const int* bins, const float* inv,
        const void* x, int xbase, int xld,
        const __hip_bfloat16* W, float* outf, const int* flagp) {
    __shared__ float xs[EPB][128];
    __shared__ float lscl[EPB];
    __shared__ int   ldst[EPB];
    int r = blockIdx.x;
    int rs = bins[r];
    int re = bins[r + 1];
    int e0 = rs + blockIdx.y * EPB;
    if (e0 >= re) return;
    int isf32 = *flagp;
    int tid = threadIdx.x;

    if (tid < EPB) {
        int e = e0 + tid;
        if (e < re) {
            int d = s_dst[e];
            ldst[tid] = d;
            lscl[tid] = inv[(long long)r * N_NODES + d];
        } else {
            ldst[tid] = 0;
            lscl[tid] = 0.0f;   // marks invalid tail edge
        }
    }
    for (int s = tid; s < EPB * 128; s += 256) {
        int er = s >> 7;
        int c = s & 127;
        int e = e0 + er;
        int ec = (e < re) ? e : (re - 1);
        int srow = s_src[ec];
        xs[er][c] = loadF(x, (long long)xbase + (long long)srow * xld + c, isf32);
    }
    __syncthreads();

    int col = tid & 127;
    int g = tid >> 7;                   // 0/1 -> edges g*8 .. g*8+7
    const __hip_bfloat16* Wr = W + ((long long)r << 14);
    float acc[8];
    for (int j = 0; j < 8; j++) acc[j] = 0.0f;
    for (int i = 0; i < 128; i++) {
        float w = __bfloat162float(Wr[i * 128 + col]);
#pragma unroll
        for (int j = 0; j < 8; j++)
            acc[j] += w * xs[g * 8 + j][i];
    }
    for (int j = 0; j < 8; j++) {
        int e = g * 8 + j;
        float s = lscl[e];
        if (s != 0.0f)
            atomicAdd(&outf[(long long)ldst[e] * 128 + col], acc[j] * s);
    }
}

// ---------- epilogues --------------------------------------------------------
__global__ void relu_store(const float* outf, void* out, int slot,
                           const int* flagp) {
    int idx = blockIdx.x * 256 + threadIdx.x;   // < N*128 exactly
    int n = idx >> 7;
    int c = idx & 127;
    float v = fmaxf(outf[idx], 0.0f);
    storeF(out, (long long)n * 512 + slot + c, *flagp, v);
}

__global__ void copy_emb(const void* emb, void* out, const int* flagp) {
    int idx = blockIdx.x * 256 + threadIdx.x;   // < N*128 exactly
    int n = idx >> 7;
    int c = idx & 127;
    int isf32 = *flagp;
    float v = loadF(emb, idx, isf32);
    storeF(out, (long long)n * 512 + 384 + c, isf32, v);
}

// ---------- launch -----------------------------------------------------------
extern "C" void kernel_launch(void* const* d_in, const int* in_sizes, int n_in,
                              void* d_out, int out_size, void* d_ws, size_t ws_size,
                              hipStream_t stream) {
    const void* emb  = d_in[0];
    const int* esrc = (const int*)d_in[1];
    const int* edst = (const int*)d_in[2];
    const int* etyp = (const int*)d_in[3];
    const void* comp[3];
    const void* basis[3];
    const void* root[3];
    const void* bias[3];
    for (int l = 0; l < 3; l++) {
        comp[l]  = d_in[4 + l * 4];
        basis[l] = d_in[5 + l * 4];
        root[l]  = d_in[6 + l * 4];
        bias[l]  = d_in[7 + l * 4];
    }

    char* ws = (char*)d_ws;
    int*   flag   = (int*)(ws + 0);                           // 256 B
    float* inv    = (float*)(ws + 256);                       // 3,840,000 B
    int*   s_src  = (int*)(ws + 3840256);                     // 2,560,000 B
    int*   s_dst  = (int*)(ws + 6400256);                     // 2,560,000 B
    int*   ctrl   = (int*)(ws + 8960256);                     // 8,192 B
    int*   hist    = ctrl + 0;                                // 48 ints
    int*   bins    = ctrl + 64;                               // 49 ints
    int*   cursorP = ctrl + 256;                              // 48*32 ints, padded
    __hip_bfloat16* W = (__hip_bfloat16*)(ws + 8968448);      // 1,572,864 B
    float* outf   = (float*)(ws + 10541312);                  // 10,240,000 B
                                                              // ends 20,781,312 B

    detect_dtype<<<1, 64, 0, stream>>>(emb, flag);
    zero_f32<<<3750, 256, 0, stream>>>(inv, R_REL * N_NODES);
    zero_i32<<<8, 256, 0, stream>>>(ctrl, 2048);

    count_kernel<<<2500, 256, 0, stream>>>(edst, etyp, inv);
    hist_reduce<<<48, 256, 0, stream>>>(inv, hist);
    inv_kernel<<<3750, 256, 0, stream>>>(inv);
    prefix_kernel<<<1, 64, 0, stream>>>(hist, bins, cursorP);
    scatter_chunk<<<(E_EDGES + SC_CHUNK - 1) / SC_CHUNK, 256, 0, stream>>>(
        esrc, edst, etyp, cursorP, s_src, s_dst);
    copy_emb<<<10000, 256, 0, stream>>>(emb, d_out, flag);

    const void* xin = emb;
    int xbase = 0;
    int xld = 128;
    const int slots[3] = {256, 128, 0};   // x1, x2, x3 column offsets
    for (int l = 0; l < 3; l++) {
        build_w<<<dim3(48, 64), 256, 0, stream>>>(comp[l], basis[l], W, flag);
        root_valu<<<20000, 128, 0, stream>>>(xin, xbase, xld, root[l], bias[l],
                                             outf, flag);
        edge_valu<<<dim3(48, 1000), 256, 0, stream>>>(s_src, s_dst, bins, inv,
                                                      xin, xbase, xld,
                                                      W, outf, flag);
        relu_store<<<10000, 256, 0, stream>>>(outf, d_out, slots[l], flag);
        xin = d_out;
        xbase = slots[l];
        xld = 512;
    }
    (void)in_sizes; (void)n_in; (void)out_size; (void)ws_size;
}

// Round 2
// 1211.861 us; speedup vs baseline: 3.0048x; 1.3990x over previous
//
#include <hip/hip_runtime.h>
#include <hip/hip_bf16.h>

#define N_NODES 20000
#define R_REL   48
#define NBASES  12
#define E_EDGES 640000
#define SC_CHUNK 2048
#define TPB_TILES 8     // 32-edge tiles per block in edge_mfma

typedef __attribute__((ext_vector_type(8))) short bf16x8;
typedef __attribute__((ext_vector_type(4))) float f32x4;

// ---------- dual-dtype scalar access (flag: 1 = fp32, 0 = bf16) -------------
__device__ inline float loadF(const void* p, long long idx, int isf32) {
    if (isf32 != 0) return ((const float*)p)[idx];
    return __bfloat162float(((const __hip_bfloat16*)p)[idx]);
}

__device__ inline void storeF(void* p, long long idx, int isf32, float v) {
    if (isf32 != 0) ((float*)p)[idx] = v;
    else ((__hip_bfloat16*)p)[idx] = __float2bfloat16(v);
}

// ---------- dtype probe ------------------------------------------------------
__global__ void detect_dtype(const void* emb, int* flag) {
    if (threadIdx.x == 0 && blockIdx.x == 0) {
        const unsigned short* h = (const unsigned short*)emb;
        int f32 = 0;
        for (int k = 0; k < 256; k++) {
            unsigned int bits = ((unsigned int)h[k]) << 16;
            float v = __uint_as_float(bits);
            if (!(fabsf(v) < 1000.0f)) f32 = 1;   // huge/NaN -> fp32 data
        }
        *flag = f32;
    }
}

// ---------- zero helpers -----------------------------------------------------
__global__ void zero_f32(float* p, int n) {
    int i = blockIdx.x * 256 + threadIdx.x;
    if (i < n) p[i] = 0.0f;
}

__global__ void zero_i32(int* p, int n) {
    int i = blockIdx.x * 256 + threadIdx.x;
    if (i < n) p[i] = 0;
}

// ---------- edge prep --------------------------------------------------------
// cnt only: scattered atomics over R*N floats (L2-resident, low contention).
__global__ void count_kernel(const int* dst, const int* typ, float* cnt) {
    int e = blockIdx.x * 256 + threadIdx.x;
    if (e < E_EDGES) {
        int t = typ[e];
        atomicAdd(&cnt[(long long)t * N_NODES + dst[e]], 1.0f);
    }
}

// hist[r] = sum over d of cnt[r*N+d]  (counts are exact small integers)
__global__ void hist_reduce(const float* cnt, int* hist) {
    __shared__ float sh[256];
    int r = blockIdx.x;
    float acc = 0.0f;
    for (int i = threadIdx.x; i < N_NODES; i += 256)
        acc += cnt[(long long)r * N_NODES + i];
    sh[threadIdx.x] = acc;
    __syncthreads();
    for (int s = 128; s > 0; s >>= 1) {
        if (threadIdx.x < s) sh[threadIdx.x] += sh[threadIdx.x + s];
        __syncthreads();
    }
    if (threadIdx.x == 0) hist[r] = (int)(sh[0] + 0.5f);
}

__global__ void inv_kernel(float* p) {
    int i = blockIdx.x * 256 + threadIdx.x;   // < R*N exactly
    float c = p[i];
    p[i] = (c > 0.0f) ? (1.0f / c) : 0.0f;
}

// cursorP is line-padded: one counter per 32 ints (128 B).
__global__ void prefix_kernel(const int* hist, int* bins, int* cursorP) {
    if (threadIdx.x == 0 && blockIdx.x == 0) {
        int acc = 0;
        for (int r = 0; r < R_REL; r++) {
            bins[r] = acc;
            cursorP[r * 32] = acc;
            acc += hist[r];
        }
        bins[R_REL] = acc;
    }
}

// Block-chunk reservation scatter: LDS histogram of a 2048-edge chunk,
// ONE global atomic per (block, relation), then conflict-free writes.
__global__ __launch_bounds__(256) void scatter_chunk(
        const int* src, const int* dst, const int* typ,
        int* cursorP, int* s_src, int* s_dst) {
    __shared__ int sh_cnt[R_REL];
    __shared__ int sh_base[R_REL];
    int b0 = blockIdx.x * SC_CHUNK;
    int tid = threadIdx.x;
    for (int t = tid; t < R_REL; t += 256) sh_cnt[t] = 0;
    __syncthreads();

    int myt[8];
    int myloc[8];
#pragma unroll 8
    for (int k = 0; k < 8; k++) {
        int e = b0 + k * 256 + tid;
        if (e < E_EDGES) {
            int t = typ[e];
            myt[k] = t;
            myloc[k] = atomicAdd(&sh_cnt[t], 1);
        } else {
            myt[k] = -1;
            myloc[k] = 0;
        }
    }
    __syncthreads();
    for (int t = tid; t < R_REL; t += 256)
        sh_base[t] = atomicAdd(&cursorP[t * 32], sh_cnt[t]);
    __syncthreads();
#pragma unroll 8
    for (int k = 0; k < 8; k++) {
        if (myt[k] >= 0) {
            int e = b0 + k * 256 + tid;
            int p = sh_base[myt[k]] + myloc[k];
            s_src[p] = src[e];
            s_dst[p] = dst[e];
        }
    }
}

// ---------- W build: Wt[r][o][i] = sum_b comp[r][b]*basis[b][i][o] ----------
// TRANSPOSED output so edge_mfma B-fragments (B[k][n], k contiguous) are
// single 16B vector loads.
__global__ void build_w(const void* comp, const void* basis,
                        __hip_bfloat16* W, const int* flagp) {
    int r = blockIdx.x;
    int idx = blockIdx.y * 256 + threadIdx.x;   // 0..16383 = i*128+o
    int isf32 = *flagp;
    float acc = 0.0f;
    for (int b = 0; b < NBASES; b++) {
        acc += loadF(comp, r * NBASES + b, isf32) *
               loadF(basis, b * 16384 + idx, isf32);
    }
    int i = idx >> 7;
    int o = idx & 127;
    W[((long long)r << 14) + o * 128 + i] = __float2bfloat16(acc);
}

// ---------- root: outf[n][o] = bias[o] + sum_i x[n][i]*root[i][o] -----------
__global__ __launch_bounds__(128) void root_valu(
        const void* x, int xbase, int xld,
        const void* root, const void* bias,
        float* outf, const int* flagp) {
    __shared__ float xs[128];
    int n = blockIdx.x;
    int o = threadIdx.x;
    int isf32 = *flagp;
    xs[o] = loadF(x, (long long)xbase + (long long)n * xld + o, isf32);
    __syncthreads();
    float acc = loadF(bias, o, isf32);
    for (int i = 0; i < 128; i++)
        acc += xs[i] * loadF(root, i * 128 + o, isf32);
    outf[(long long)n * 128 + o] = acc;
}

// ---------- edge: outf[dst] += inv * (x[src] @ W_r), via MFMA ---------------
// Block = 4 waves, one relation r, up to 8 tiles of 32 edges.
// Wave w: rowTile = w&1 (16 edges), cols 64*(w>>1)..+63 (4 col-tiles of 16).
// B-fragments held in registers across all tiles (W_r constant per block).
// Fragment maps (m89-verified family):
//   A[m][k]: m=lane&15, k=(lane>>4)*8+j ;  B[k][n]: n=lane&15, k=(lane>>4)*8+j
//   D[m][n]: n=lane&15, m=(lane>>4)*4+q
__global__ __launch_bounds__(256) void edge_mfma(
        const int* s_src, const int* s_dst, const int* bins, const float* inv,
        const void* x, int xbase, int xld,
        const __hip_bfloat16* Wt, float* outf, const int* flagp) {
    __shared__ __hip_bfloat16 xs[32][136];   // pitch 136: spreads LDS banks
    __shared__ float lscl[32];
    __shared__ int   ldst[32];
    int r = blockIdx.x;
    int rs = bins[r];
    int re = bins[r + 1];
    int base = rs + blockIdx.y * (TPB_TILES * 32);
    if (base >= re) return;
    int isf32 = *flagp;
    int tid = threadIdx.x;
    int lane = tid & 63;
    int w = tid >> 6;
    int rowTile = w & 1;
    int colBase = (w >> 1) * 64;
    int lr = lane & 15;     // fragment row (A) / col (B,D)
    int lk = lane >> 4;     // k-group 0..3 (A,B) / row-group (D)

    // B fragments: 4 col-tiles x 4 K-steps, 16B vector loads from L2.
    bf16x8 bfrag[4][4];
    const __hip_bfloat16* Wr = Wt + ((long long)r << 14);
#pragma unroll
    for (int ct = 0; ct < 4; ct++) {
        const __hip_bfloat16* wp = Wr + (long long)(colBase + ct * 16 + lr) * 128;
#pragma unroll
        for (int k = 0; k < 4; k++)
            bfrag[ct][k] = *(const bf16x8*)(wp + k * 32 + lk * 8);
    }

    for (int t = 0; t < TPB_TILES; t++) {
        int e0 = base + t * 32;
        if (e0 >= re) break;
        __syncthreads();    // xs reuse: previous tile's reads done
        if (tid < 32) {
            int e = e0 + tid;
            if (e < re) {
                int d = s_dst[e];
                ldst[tid] = d;
                lscl[tid] = inv[(long long)r * N_NODES + d];
            } else {
                ldst[tid] = 0;
                lscl[tid] = 0.0f;   // tail edge: contribution dropped
            }
        }
        // stage 32 x-rows as bf16, 4 elems per thread-iter (vectorized)
        for (int s = tid; s < 32 * 32; s += 256) {
            int er = s >> 5;
            int c4 = (s & 31) << 2;
            int e = e0 + er;
            int ec = (e < re) ? e : (re - 1);
            long long rb = (long long)xbase + (long long)s_src[ec] * xld + c4;
            ushort4 pk;
            if (isf32) {
                const float4 f = *(const float4*)((const float*)x + rb);
                __hip_bfloat16 h0 = __float2bfloat16(f.x);
                __hip_bfloat16 h1 = __float2bfloat16(f.y);
                __hip_bfloat16 h2 = __float2bfloat16(f.z);
                __hip_bfloat16 h3 = __float2bfloat16(f.w);
                pk.x = *(unsigned short*)&h0;
                pk.y = *(unsigned short*)&h1;
                pk.z = *(unsigned short*)&h2;
                pk.w = *(unsigned short*)&h3;
            } else {
                pk = *(const ushort4*)((const unsigned short*)x + rb);
            }
            *(ushort4*)&xs[er][c4] = pk;
        }
        __syncthreads();

        f32x4 acc[4];
#pragma unroll
        for (int ct = 0; ct < 4; ct++) acc[ct] = (f32x4){0.f, 0.f, 0.f, 0.f};
#pragma unroll
        for (int k = 0; k < 4; k++) {
            bf16x8 a = *(const bf16x8*)(&xs[rowTile * 16 + lr][k * 32 + lk * 8]);
#pragma unroll
            for (int ct = 0; ct < 4; ct++)
                acc[ct] = __builtin_amdgcn_mfma_f32_16x16x32_bf16(
                    a, bfrag[ct][k], acc[ct], 0, 0, 0);
        }
        // epilogue: scale by inv, atomicAdd into outf
#pragma unroll
        for (int q = 0; q < 4; q++) {
            int row = rowTile * 16 + lk * 4 + q;
            float sa = lscl[row];
            if (sa != 0.0f) {
                long long ob = (long long)ldst[row] * 128 + colBase + lr;
#pragma unroll
                for (int ct = 0; ct < 4; ct++)
                    atomicAdd(&outf[ob + ct * 16], acc[ct][q] * sa);
            }
        }
    }
}

// ---------- epilogues --------------------------------------------------------
__global__ void relu_store(const float* outf, void* out, int slot,
                           const int* flagp) {
    int idx = blockIdx.x * 256 + threadIdx.x;   // < N*128 exactly
    int n = idx >> 7;
    int c = idx & 127;
    float v = fmaxf(outf[idx], 0.0f);
    storeF(out, (long long)n * 512 + slot + c, *flagp, v);
}

__global__ void copy_emb(const void* emb, void* out, const int* flagp) {
    int idx = blockIdx.x * 256 + threadIdx.x;   // < N*128 exactly
    int n = idx >> 7;
    int c = idx & 127;
    int isf32 = *flagp;
    float v = loadF(emb, idx, isf32);
    storeF(out, (long long)n * 512 + 384 + c, isf32, v);
}

// ---------- launch -----------------------------------------------------------
extern "C" void kernel_launch(void* const* d_in, const int* in_sizes, int n_in,
                              void* d_out, int out_size, void* d_ws, size_t ws_size,
                              hipStream_t stream) {
    const void* emb  = d_in[0];
    const int* esrc = (const int*)d_in[1];
    const int* edst = (const int*)d_in[2];
    const int* etyp = (const int*)d_in[3];
    const void* comp[3];
    const void* basis[3];
    const void* root[3];
    const void* bias[3];
    for (int l = 0; l < 3; l++) {
        comp[l]  = d_in[4 + l * 4];
        basis[l] = d_in[5 + l * 4];
        root[l]  = d_in[6 + l * 4];
        bias[l]  = d_in[7 + l * 4];
    }

    char* ws = (char*)d_ws;
    int*   flag   = (int*)(ws + 0);                           // 256 B
    float* inv    = (float*)(ws + 256);                       // 3,840,000 B
    int*   s_src  = (int*)(ws + 3840256);                     // 2,560,000 B
    int*   s_dst  = (int*)(ws + 6400256);                     // 2,560,000 B
    int*   ctrl   = (int*)(ws + 8960256);                     // 8,192 B
    int*   hist    = ctrl + 0;                                // 48 ints
    int*   bins    = ctrl + 64;                               // 49 ints
    int*   cursorP = ctrl + 256;                              // 48*32 ints
    __hip_bfloat16* W = (__hip_bfloat16*)(ws + 8968448);      // 1,572,864 B
    float* outf   = (float*)(ws + 10541312);                  // 10,240,000 B

    detect_dtype<<<1, 64, 0, stream>>>(emb, flag);
    zero_f32<<<3750, 256, 0, stream>>>(inv, R_REL * N_NODES);
    zero_i32<<<8, 256, 0, stream>>>(ctrl, 2048);

    count_kernel<<<2500, 256, 0, stream>>>(edst, etyp, inv);
    hist_reduce<<<48, 256, 0, stream>>>(inv, hist);
    inv_kernel<<<3750, 256, 0, stream>>>(inv);
    prefix_kernel<<<1, 64, 0, stream>>>(hist, bins, cursorP);
    scatter_chunk<<<(E_EDGES + SC_CHUNK - 1) / SC_CHUNK, 256, 0, stream>>>(
        esrc, edst, etyp, cursorP, s_src, s_dst);
    copy_emb<<<10000, 256, 0, stream>>>(emb, d_out, flag);

    const void* xin = emb;
    int xbase = 0;
    int xld = 128;
    const int slots[3] = {256, 128, 0};   // x1, x2, x3 column offsets
    for (int l = 0; l < 3; l++) {
        build_w<<<dim3(48, 64), 256, 0, stream>>>(comp[l], basis[l], W, flag);
        root_valu<<<20000, 128, 0, stream>>>(xin, xbase, xld, root[l], bias[l],
                                             outf, flag);
        // 64*256 = 16384 edges/relation capacity; uniform-random types give
        // max/rel ~13.7K << 16384.
        edge_mfma<<<dim3(48, 64), 256, 0, stream>>>(s_src, s_dst, bins, inv,
                                                    xin, xbase, xld,
                                                    W, outf, flag);
        relu_store<<<10000, 256, 0, stream>>>(outf, d_out, slots[l], flag);
        xin = d_out;
        xbase = slots[l];
        xld = 512;
    }
    (void)in_sizes; (void)n_in; (void)out_size; (void)ws_size;
}

// Round 3
// 1056.873 us; speedup vs baseline: 3.4455x; 1.1466x over previous
//
#include <hip/hip_runtime.h>
#include <hip/hip_bf16.h>

#define N_NODES 20000
#define R_REL   48
#define NBASES  12
#define E_EDGES 640000
#define KDIM    1664        // 12*128 (bases) + 128 (root)
#define KSTEPS  52          // 1664 / 32
#define XPITCH  1672        // LDS row pitch (bf16): +16B pad -> 2-way banks only
#define NBLK_SCAN 79        // ceil(20000/256)

typedef __attribute__((ext_vector_type(8))) short bf16x8;
typedef __attribute__((ext_vector_type(4))) float f32x4;

// ---------- dual-dtype scalar access (flag: 1 = fp32, 0 = bf16) -------------
__device__ inline float loadF(const void* p, long long idx, int isf32) {
    if (isf32 != 0) return ((const float*)p)[idx];
    return __bfloat162float(((const __hip_bfloat16*)p)[idx]);
}

__device__ inline void storeF(void* p, long long idx, int isf32, float v) {
    if (isf32 != 0) ((float*)p)[idx] = v;
    else ((__hip_bfloat16*)p)[idx] = __float2bfloat16(v);
}

// ---------- dtype probe ------------------------------------------------------
__global__ void detect_dtype(const void* emb, int* flag) {
    if (threadIdx.x == 0 && blockIdx.x == 0) {
        const unsigned short* h = (const unsigned short*)emb;
        int f32 = 0;
        for (int k = 0; k < 256; k++) {
            unsigned int bits = ((unsigned int)h[k]) << 16;
            float v = __uint_as_float(bits);
            if (!(fabsf(v) < 1000.0f)) f32 = 1;   // huge/NaN -> fp32 data
        }
        *flag = f32;
    }
}

// ---------- zero helper ------------------------------------------------------
__global__ void zero_i32(int* p, int n) {
    int i = blockIdx.x * 256 + threadIdx.x;
    if (i < n) p[i] = 0;
}

// ---------- dst-sort pipeline ------------------------------------------------
// Counters line-padded (1 per 32 ints = 128 B): max 32 same-line serialized
// atomics (same dst) instead of ~1024.
__global__ void countd_kernel(const int* dst, int* cntdP) {
    int e = blockIdx.x * 256 + threadIdx.x;
    if (e < E_EDGES) atomicAdd(&cntdP[dst[e] * 32], 1);
}

__global__ void scan_a(const int* cntdP, int* binsd, int* psum) {
    __shared__ int sh[256];
    int t = threadIdx.x;
    int i = blockIdx.x * 256 + t;
    int v = (i < N_NODES) ? cntdP[i * 32] : 0;
    sh[t] = v;
    __syncthreads();
    for (int off = 1; off < 256; off <<= 1) {
        int add = (t >= off) ? sh[t - off] : 0;
        __syncthreads();
        sh[t] += add;
        __syncthreads();
    }
    if (i < N_NODES) binsd[i] = sh[t] - v;      // local exclusive
    if (t == 255) psum[blockIdx.x] = sh[255];   // block total
}

__global__ void scan_b(int* psum, int* binsd) {
    if (threadIdx.x == 0 && blockIdx.x == 0) {
        int acc = 0;
        for (int b = 0; b < NBLK_SCAN; b++) {
            int t = psum[b]; psum[b] = acc; acc += t;
        }
        binsd[N_NODES] = acc;   // == E_EDGES
    }
}

__global__ void scan_c(int* binsd, const int* psum, int* cursordP) {
    int i = blockIdx.x * 256 + threadIdx.x;
    if (i < N_NODES) {
        int v = binsd[i] + psum[i >> 8];
        binsd[i] = v;
        cursordP[i * 32] = v;
    }
}

// s_pack[e] = src | (rel << 20)   (src < 2^20, rel < 48)
__global__ void scatter_d(const int* src, const int* dst, const int* typ,
                          int* cursordP, int* s_pack) {
    int e = blockIdx.x * 256 + threadIdx.x;
    if (e < E_EDGES) {
        int p = atomicAdd(&cursordP[dst[e] * 32], 1);
        s_pack[p] = src[e] | (typ[e] << 20);
    }
}

// ---------- Wcat build: Wt[o][k], k = b*128+i -> basis[b][i][o]; tail = root
__global__ void build_wcat(const void* basis, const void* root,
                           __hip_bfloat16* Wt, const int* flagp) {
    int o = blockIdx.x;                       // 0..127
    int k = blockIdx.y * 256 + threadIdx.x;   // 0..1663
    if (k >= KDIM) return;
    int isf32 = *flagp;
    float v;
    if (k < NBASES * 128) {
        int b = k >> 7, i = k & 127;
        v = loadF(basis, b * 16384 + i * 128 + o, isf32);
    } else {
        v = loadF(root, (k - NBASES * 128) * 128 + o, isf32);
    }
    Wt[(long long)o * KDIM + k] = __float2bfloat16(v);
}

// ---------- fused layer: aggregate-in-registers + MFMA GEMM, no atomics -----
// Block = 4 waves, 16 dst rows. Phase 1: wave w aggregates rows w*4+dd
// (u[b][col] in 24 VGPR/lane, per-run relation counts in LDS). Phase 2:
// A-tile [16][1664] bf16 in LDS x Wt -> 16x128 outputs, bias+relu+store.
// Fragment maps identical to R2's on-device-verified edge_mfma.
__global__ __launch_bounds__(256) void fused_layer(
        const int* s_pack, const int* binsd, const void* comp,
        const void* x, int xbase, int xld,
        const __hip_bfloat16* Wt, const void* bias,
        void* out, int slot, const int* flagp) {
    __shared__ __hip_bfloat16 xs[16][XPITCH];       // 53.5 KB A-tile
    __shared__ float scomp[R_REL * NBASES];         // comp, f32
    __shared__ int   shcnt[4][R_REL];
    __shared__ float shinv[4][R_REL];
    int isf32 = *flagp;
    int tid = threadIdx.x;
    int lane = tid & 63;
    int w = tid >> 6;
    int nb = blockIdx.x;

    for (int i = tid; i < R_REL * NBASES; i += 256)
        scomp[i] = loadF(comp, i, isf32);
    // (first scomp use is after the dd=0 barriers below)

    int col = lane * 2;                              // 2 cols per lane
    for (int dd = 0; dd < 4; dd++) {
        int row = w * 4 + dd;
        int dstn = nb * 16 + row;
        int e0 = binsd[dstn];
        int e1 = binsd[dstn + 1];

        if (lane < R_REL) shcnt[w][lane] = 0;
        __syncthreads();
        for (int e = e0 + lane; e < e1; e += 64)
            atomicAdd(&shcnt[w][s_pack[e] >> 20], 1);
        __syncthreads();
        if (lane < R_REL) {
            int c = shcnt[w][lane];
            shinv[w][lane] = (c > 0) ? (1.0f / (float)c) : 0.0f;
        }
        __syncthreads();

        float accA[NBASES], accB[NBASES];
#pragma unroll
        for (int b = 0; b < NBASES; b++) { accA[b] = 0.0f; accB[b] = 0.0f; }

        // 1-deep software pipeline: next edge's x-pair loads while FMA-ing cur
        int e = e0;
        int cp = 0; float cx0 = 0.0f, cx1 = 0.0f;
        if (e < e1) {
            cp = s_pack[e];
            long long rb = (long long)xbase +
                           (long long)(cp & 0xFFFFF) * xld + col;
            if (isf32) {
                float2 f = *(const float2*)((const float*)x + rb);
                cx0 = f.x; cx1 = f.y;
            } else {
                unsigned int u = *(const unsigned int*)
                                  ((const unsigned short*)x + rb);
                cx0 = __uint_as_float(u << 16);
                cx1 = __uint_as_float(u & 0xFFFF0000u);
            }
        }
        while (e < e1) {
            int p = cp; float x0 = cx0, x1 = cx1;
            int en = e + 1;
            if (en < e1) {
                cp = s_pack[en];
                long long rb = (long long)xbase +
                               (long long)(cp & 0xFFFFF) * xld + col;
                if (isf32) {
                    float2 f = *(const float2*)((const float*)x + rb);
                    cx0 = f.x; cx1 = f.y;
                } else {
                    unsigned int u = *(const unsigned int*)
                                      ((const unsigned short*)x + rb);
                    cx0 = __uint_as_float(u << 16);
                    cx1 = __uint_as_float(u & 0xFFFF0000u);
                }
            }
            int r_ = p >> 20;
            float sc = shinv[w][r_];
            float x0s = x0 * sc, x1s = x1 * sc;
            const float4 c0 = *(const float4*)&scomp[r_ * NBASES];
            const float4 c1 = *(const float4*)&scomp[r_ * NBASES + 4];
            const float4 c2 = *(const float4*)&scomp[r_ * NBASES + 8];
            accA[0] += c0.x * x0s;  accB[0] += c0.x * x1s;
            accA[1] += c0.y * x0s;  accB[1] += c0.y * x1s;
            accA[2] += c0.z * x0s;  accB[2] += c0.z * x1s;
            accA[3] += c0.w * x0s;  accB[3] += c0.w * x1s;
            accA[4] += c1.x * x0s;  accB[4] += c1.x * x1s;
            accA[5] += c1.y * x0s;  accB[5] += c1.y * x1s;
            accA[6] += c1.z * x0s;  accB[6] += c1.z * x1s;
            accA[7] += c1.w * x0s;  accB[7] += c1.w * x1s;
            accA[8] += c2.x * x0s;  accB[8] += c2.x * x1s;
            accA[9] += c2.y * x0s;  accB[9] += c2.y * x1s;
            accA[10] += c2.z * x0s; accB[10] += c2.z * x1s;
            accA[11] += c2.w * x0s; accB[11] += c2.w * x1s;
            e = en;
        }

        // write aggregate row to A-tile (bf16 pairs, 4B writes, 2-way banks)
#pragma unroll
        for (int b = 0; b < NBASES; b++) {
            __hip_bfloat16 h0 = __float2bfloat16(accA[b]);
            __hip_bfloat16 h1 = __float2bfloat16(accB[b]);
            unsigned int pk = ((unsigned int)*(unsigned short*)&h1 << 16) |
                              (unsigned int)*(unsigned short*)&h0;
            *(unsigned int*)&xs[row][b * 128 + col] = pk;
        }
        // root slot: x[dstn] itself at k = 1536..1663
        {
            long long rb = (long long)xbase + (long long)dstn * xld + col;
            unsigned int pk;
            if (isf32) {
                float2 f = *(const float2*)((const float*)x + rb);
                __hip_bfloat16 h0 = __float2bfloat16(f.x);
                __hip_bfloat16 h1 = __float2bfloat16(f.y);
                pk = ((unsigned int)*(unsigned short*)&h1 << 16) |
                     (unsigned int)*(unsigned short*)&h0;
            } else {
                pk = *(const unsigned int*)((const unsigned short*)x + rb);
            }
            *(unsigned int*)&xs[row][NBASES * 128 + col] = pk;
        }
    }
    __syncthreads();

    // ---- phase 2: A-tile [16][1664] x Wt -> 16 x 128, wave w owns 32 cols
    int lr = lane & 15;      // A row / B,D col-in-tile
    int lk = lane >> 4;      // k-group / D row-group
    int colBase = w * 32;
    f32x4 acc0 = {0.f, 0.f, 0.f, 0.f};
    f32x4 acc1 = {0.f, 0.f, 0.f, 0.f};
    const __hip_bfloat16* w0 = Wt + (long long)(colBase + lr) * KDIM;
    const __hip_bfloat16* w1 = Wt + (long long)(colBase + 16 + lr) * KDIM;
#pragma unroll 4
    for (int ks = 0; ks < KSTEPS; ks++) {
        int ko = ks * 32 + lk * 8;
        bf16x8 a  = *(const bf16x8*)&xs[lr][ko];
        bf16x8 b0 = *(const bf16x8*)(w0 + ko);
        bf16x8 b1 = *(const bf16x8*)(w1 + ko);
        acc0 = __builtin_amdgcn_mfma_f32_16x16x32_bf16(a, b0, acc0, 0, 0, 0);
        acc1 = __builtin_amdgcn_mfma_f32_16x16x32_bf16(a, b1, acc1, 0, 0, 0);
    }
    float bi0 = loadF(bias, colBase + lr, isf32);
    float bi1 = loadF(bias, colBase + 16 + lr, isf32);
#pragma unroll
    for (int q = 0; q < 4; q++) {
        int row = lk * 4 + q;
        long long ob = (long long)(nb * 16 + row) * 512 + slot;
        storeF(out, ob + colBase + lr,      isf32, fmaxf(acc0[q] + bi0, 0.0f));
        storeF(out, ob + colBase + 16 + lr, isf32, fmaxf(acc1[q] + bi1, 0.0f));
    }
}

// ---------- emb passthrough --------------------------------------------------
__global__ void copy_emb(const void* emb, void* out, const int* flagp) {
    int idx = blockIdx.x * 256 + threadIdx.x;   // < N*128 exactly
    int n = idx >> 7;
    int c = idx & 127;
    int isf32 = *flagp;
    float v = loadF(emb, idx, isf32);
    storeF(out, (long long)n * 512 + 384 + c, isf32, v);
}

// ---------- launch -----------------------------------------------------------
extern "C" void kernel_launch(void* const* d_in, const int* in_sizes, int n_in,
                              void* d_out, int out_size, void* d_ws, size_t ws_size,
                              hipStream_t stream) {
    const void* emb  = d_in[0];
    const int* esrc = (const int*)d_in[1];
    const int* edst = (const int*)d_in[2];
    const int* etyp = (const int*)d_in[3];
    const void* comp[3];
    const void* basis[3];
    const void* root[3];
    const void* bias[3];
    for (int l = 0; l < 3; l++) {
        comp[l]  = d_in[4 + l * 4];
        basis[l] = d_in[5 + l * 4];
        root[l]  = d_in[6 + l * 4];
        bias[l]  = d_in[7 + l * 4];
    }

    char* ws = (char*)d_ws;
    int*   flag     = (int*)(ws + 0);                       // 256 B
    int*   s_pack   = (int*)(ws + 256);                     // 2,560,000 B
    int*   cntdP    = (int*)(ws + 2560256);                 // 2,560,000 B (padded x32)
    int*   cursordP = (int*)(ws + 5120256);                 // 2,560,000 B (padded x32)
    int*   binsd    = (int*)(ws + 7680256);                 // 80,256 B (N+1)
    int*   psum     = (int*)(ws + 7760512);                 // 512 B
    __hip_bfloat16* Wt = (__hip_bfloat16*)(ws + 7761024);   // 425,984 B
                                                            // ends 8,187,008 B

    detect_dtype<<<1, 64, 0, stream>>>(emb, flag);
    zero_i32<<<2500, 256, 0, stream>>>(cntdP, N_NODES * 32);

    countd_kernel<<<2500, 256, 0, stream>>>(edst, cntdP);
    scan_a<<<NBLK_SCAN, 256, 0, stream>>>(cntdP, binsd, psum);
    scan_b<<<1, 64, 0, stream>>>(psum, binsd);
    scan_c<<<NBLK_SCAN, 256, 0, stream>>>(binsd, psum, cursordP);
    scatter_d<<<2500, 256, 0, stream>>>(esrc, edst, etyp, cursordP, s_pack);
    copy_emb<<<10000, 256, 0, stream>>>(emb, d_out, flag);

    const void* xin = emb;
    int xbase = 0;
    int xld = 128;
    const int slots[3] = {256, 128, 0};   // x1, x2, x3 column offsets
    for (int l = 0; l < 3; l++) {
        build_wcat<<<dim3(128, 7), 256, 0, stream>>>(basis[l], root[l], Wt, flag);
        fused_layer<<<1250, 256, 0, stream>>>(s_pack, binsd, comp[l],
                                              xin, xbase, xld,
                                              Wt, bias[l], d_out, slots[l], flag);
        xin = d_out;
        xbase = slots[l];
        xld = 512;
    }
    (void)in_sizes; (void)n_in; (void)out_size; (void)ws_size;
}